// Round 3
// baseline (368.579 us; speedup 1.0000x reference)
//
#include <hip/hip_runtime.h>

// Problem constants
#define NT   365
#define NS   256
#define NH   256
#define NG   32
#define NR   16
#define HID  256
#define NX   38           // 6 + NG
#define M_   (NT*NS)      // 93440
#define MPAD (368*NS)     // 94208 (padded to 46 t-groups of 8)
#define TOUT (NT-NR+1)    // 350
#define TC   46           // t-groups of 8
#define PSEG ((size_t)1024*TC*512)   // u16 per seg plane

typedef __attribute__((ext_vector_type(8))) short short8;
typedef __attribute__((ext_vector_type(4))) short short4v;
typedef __attribute__((ext_vector_type(4))) float floatx4;
typedef unsigned short u16;

__device__ __forceinline__ u16 f2bf(float f) {
    unsigned u = __float_as_uint(f);
    u = (u + 0x7FFFu + ((u >> 16) & 1u)) >> 16;   // RNE
    return (u16)u;
}
__device__ __forceinline__ float bf2f(u16 u) {
    return __uint_as_float(((unsigned)u) << 16);
}
__device__ __forceinline__ float sigmoidf_(float x) { return 1.f / (1.f + __expf(-x)); }

// Fragment-tile layout (R17): A (h1b) and B (w2tT) are stored as 16x32 bf16
// MFMA tiles, each tile = 64 lanes x 8 u16 contiguous (1 KB). Element (r, c)
// of a tile lives at lane = (r&15) | (((c&31)>>3)<<4), pos = c&7 — exactly the
// per-lane fragment the old LDS ds_read path produced. A fragment load is ONE
// coalesced global_load_dwordx4 (base + lane*16B).
__device__ __forceinline__ size_t frag_idx(int row, int col, int row_tiles_stride_unused) {
    return 0; // (unused helper placeholder)
}

// ---------------- k_prep: pre(365) + cvtT3(416) + mlp1(32) = 813 blocks ----------------
__global__ __launch_bounds__(256) void k_prep(const float* __restrict__ x,
                                              float* __restrict__ ps, float* __restrict__ plc,
                                              float* __restrict__ e2, float* __restrict__ out,
                                              const float* __restrict__ tw2, u16* __restrict__ w2tT,
                                              const float* __restrict__ fw2, u16* __restrict__ w2tW,
                                              const float* __restrict__ rw2, u16* __restrict__ w2tR,
                                              const float* __restrict__ xc,
                                              const float* __restrict__ wW, const float* __restrict__ bW,
                                              const float* __restrict__ wR, const float* __restrict__ bR,
                                              u16* __restrict__ h1W, u16* __restrict__ h1R) {
    int bx = blockIdx.x, tid = threadIdx.x;
    if (bx < 365) {
        // ---- pre body (+ zero out) ----
        int m = bx * 256 + tid;
        if (m < TOUT*NS) out[m] = 0.f;
        float P  = x[m*6+0], E = x[m*6+1], T1 = x[m*6+2], T2 = x[m*6+3];
        float vf;
        if (T2 <= 0.f)      vf = 1.f;
        else if (T1 >= 0.f) vf = 0.f;
        else {
            float ratio = (T1 + T2) / (T2 - T1);
            ratio = fminf(fmaxf(ratio, -1.f), 1.f);
            vf = acosf(ratio) * (1.f / 3.1415f);
        }
        ps[m]  = P * vf;
        plc[m] = P * (1.f - vf);
        e2[m]  = 2.f * E;
    } else if (bx < 781) {
        // ---- cvtT3 body ----
        __shared__ u16 tile[64][65];
        int i2 = bx - 365;
        int bn_ = i2 % 104, bk = i2 / 104;
        const float* w; u16* wt; int N, bn; bool frag;
        if (bn_ < 12)      { w = tw2; wt = w2tT; N = 768;  bn = bn_;      frag = true;  }
        else if (bn_ < 40) { w = fw2; wt = w2tW; N = 1792; bn = bn_ - 12; frag = false; }
        else               { w = rw2; wt = w2tR; N = 4096; bn = bn_ - 40; frag = false; }
        for (int i = tid; i < 64*64; i += 256) {
            int kk = i >> 6, nn = i & 63;
            tile[nn][kk] = f2bf(w[(size_t)(bk*64 + kk)*N + bn*64 + nn]);
        }
        __syncthreads();
        for (int i = tid; i < 64*64; i += 256) {
            int nn = i >> 6, kk = i & 63;
            int n = bn*64 + nn, k = bk*64 + kk;
            if (frag) {
                // fragment-tile layout for gemm2's B
                int ntile = n >> 4, kg = k >> 5;
                int lane2 = (n & 15) | (((k & 31) >> 3) << 4);
                wt[(((size_t)(ntile*8 + kg)) << 9) + (lane2 << 3) + (k & 7)] = tile[nn][kk];
            } else {
                wt[(size_t)n*256 + k] = tile[nn][kk];
            }
        }
    } else {
        // ---- mlp1 body ----
        int b = bx - 781;                       // 0..31: net*16 + grp
        int net = b >> 4, grp = b & 15;
        const float* w1 = net ? wR : wW;
        const float* b1 = net ? bR : bW;
        u16* o = net ? h1R : h1W;
        int s0 = grp * 16, j = tid;
        __shared__ float xs1[16][NG];
        for (int i = j; i < 16*NG; i += 256) xs1[i >> 5][i & 31] = xc[s0*NG + i];
        __syncthreads();
        float acc[16];
        float bb = b1[j];
#pragma unroll
        for (int si = 0; si < 16; ++si) acc[si] = bb;
        for (int g = 0; g < NG; ++g) {
            float w = w1[g*HID + j];
#pragma unroll
            for (int si = 0; si < 16; ++si) acc[si] += xs1[si][g] * w;
        }
#pragma unroll
        for (int si = 0; si < 16; ++si) o[(s0 + si)*256 + j] = f2bf(tanhf(acc[si]));
    }
}

// ---------------- k_mid: gemmS<0>(28) + gemmS<1>(64) + fcT1(2944) = 3036 blocks ----------------
__global__ __launch_bounds__(256) void k_mid(const u16* __restrict__ h1W, const u16* __restrict__ w2tW,
                                             const float* __restrict__ fb2, float* __restrict__ wlog,
                                             const u16* __restrict__ h1R, const u16* __restrict__ w2tR,
                                             const float* __restrict__ rb2, float* __restrict__ rbuf,
                                             const float* __restrict__ x, const float* __restrict__ xc,
                                             const float* __restrict__ tw1, const float* __restrict__ tb1,
                                             u16* __restrict__ h1b) {
    int bx = blockIdx.x, tid = threadIdx.x;
    if (bx < 92) {
        // ---- gemmS body (mode 0: bx<28, mode 1: else) ----
        int mode, bm, bn, Nn;
        const u16 *A, *B; const float* bias; float* outp;
        if (bx < 28) { mode = 0; bm = bx % 2;        bn = bx / 2;        Nn = 1792; A = h1W; B = w2tW; bias = fb2; outp = wlog; }
        else         { mode = 1; bm = (bx - 28) % 2; bn = (bx - 28) / 2; Nn = 4096; A = h1R; B = w2tR; bias = rb2; outp = rbuf; }
        int wave = tid >> 6, lane = tid & 63;
        __shared__ __align__(16) u16 As[128*32];
        __shared__ __align__(16) u16 Bs[128*32];
        floatx4 acc[4][4];
#pragma unroll
        for (int i = 0; i < 4; ++i)
#pragma unroll
            for (int jj = 0; jj < 4; ++jj) acc[i][jj] = (floatx4)(0.f);
        int m0 = bm*128, n0 = bn*128;
        int rA = tid >> 2, cA = (tid & 3) * 8;
        int wm = (wave >> 1)*64, wn = (wave & 1)*64, lr = lane & 15, lq = lane >> 4;
        for (int k0 = 0; k0 < 256; k0 += 32) {
            short8 a0  = *(const short8*)(A + (m0 + rA     )*256 + k0 + cA);
            short8 a1  = *(const short8*)(A + (m0 + rA + 64)*256 + k0 + cA);
            short8 bv0 = *(const short8*)(B + (n0 + rA     )*256 + k0 + cA);
            short8 bv1 = *(const short8*)(B + (n0 + rA + 64)*256 + k0 + cA);
            __syncthreads();
            *(short8*)(As + rA*32 + cA)        = a0;
            *(short8*)(As + (rA + 64)*32 + cA) = a1;
            *(short8*)(Bs + rA*32 + cA)        = bv0;
            *(short8*)(Bs + (rA + 64)*32 + cA) = bv1;
            __syncthreads();
            short8 af[4], bf[4];
#pragma unroll
            for (int i = 0; i < 4; ++i)
                af[i] = *(const short8*)(As + (wm + i*16 + lr)*32 + lq*8);
#pragma unroll
            for (int jj = 0; jj < 4; ++jj)
                bf[jj] = *(const short8*)(Bs + (wn + jj*16 + lr)*32 + lq*8);
#pragma unroll
            for (int i = 0; i < 4; ++i)
#pragma unroll
                for (int jj = 0; jj < 4; ++jj)
                    acc[i][jj] = __builtin_amdgcn_mfma_f32_16x16x32_bf16(af[i], bf[jj], acc[i][jj], 0, 0, 0);
        }
#pragma unroll
        for (int jj = 0; jj < 4; ++jj) {
            int n_glob = n0 + wn + jj*16 + lr;
            float bv = bias[n_glob];
            int hg = (n0 + wn + jj*16) >> 4;
#pragma unroll
            for (int i = 0; i < 4; ++i) {
#pragma unroll
                for (int rr = 0; rr < 4; ++rr) {
                    int m = m0 + wm + i*16 + lq*4 + rr;
                    float v = acc[i][jj][rr] + bv;
                    if (mode == 0) {
                        outp[(size_t)m*Nn + n_glob] = v;
                    } else {
                        v = fmaxf(v, 0.f);
                        float mx = v;
#pragma unroll
                        for (int d = 1; d < 16; d <<= 1) mx = fmaxf(mx, __shfl_xor(mx, d, 64));
                        float e = __expf(v - mx);
                        float sm = e;
#pragma unroll
                        for (int d = 1; d < 16; d <<= 1) sm += __shfl_xor(sm, d, 64);
                        outp[(size_t)m*4096 + hg*16 + lr] = e / sm;
                    }
                }
            }
        }
    } else {
        // ---- fcT1 body: writes h1b in fragment-tile layout ----
        int m0 = (bx - 92) * 32;
        int j = tid;
        __shared__ float xs[32][NX + 2];
        for (int idx = j; idx < 32*NX; idx += 256) {
            int rr = idx / NX, c = idx % NX;
            int m = m0 + rr;
            int mc = m < M_ ? m : M_ - 1;
            int s = mc & (NS - 1);
            xs[rr][c] = (c < 6) ? x[mc*6 + c] : xc[s*NG + (c - 6)];
        }
        __syncthreads();
        float acc[32];
        float b = tb1[j];
#pragma unroll
        for (int rr = 0; rr < 32; ++rr) acc[rr] = b;
        for (int g = 0; g < NX; ++g) {
            float w = tw1[g*HID + j];
#pragma unroll
            for (int rr = 0; rr < 32; ++rr) acc[rr] += xs[rr][g] * w;
        }
        int kg = j >> 5;
        int lane_hi = ((j & 31) >> 3) << 4;
        int pos = j & 7;
#pragma unroll
        for (int rr = 0; rr < 32; ++rr) {
            int m = m0 + rr;
            int mt = m >> 4;
            int lane2 = (m & 15) | lane_hi;
            h1b[(((size_t)(mt*8 + kg)) << 9) + (lane2 << 3) + pos] = f2bf(tanhf(acc[rr]));
        }
    }
}

// ---------------- k_g2p: fcw_post (blocks 0..255) + gemm2 (blocks 256..4671) ----------------
// R17: gemm2 is LDS-free and barrier-free. A (h1b) and B (w2tT) are in
// fragment-tile layout, so every fragment is one coalesced global_load_dwordx4
// (L2/L3-resident). 2-deep register pipeline over the 8 K-steps; waves fully
// decoupled (no __syncthreads in the GEMM path at all).
__global__ __launch_bounds__(256) void k_g2p(const u16* __restrict__ h1b,
                                             const u16* __restrict__ w2t,
                                             const float* __restrict__ b2,
                                             const float* __restrict__ plc,
                                             const float* __restrict__ e2,
                                             u16* __restrict__ Pc,
                                             const float* __restrict__ wlog,
                                             float* __restrict__ par) {
    int tid = threadIdx.x;

    if (blockIdx.x < 256) {
        // ---- fcw_post body ----
        __shared__ float red[256];
        int s = blockIdx.x, j = tid;
        const float* L = wlog + (size_t)s*1792;
        float o0 = L[j], o1 = L[256+j], o2 = L[512+j], o3 = L[768+j],
              o4 = L[1024+j], o5 = L[1280+j], o6 = L[1536+j];
        red[j] = o6; __syncthreads();
        for (int st = 128; st > 0; st >>= 1) {
            if (j < st) red[j] = fmaxf(red[j], red[j+st]);
            __syncthreads();
        }
        float mx = red[0]; __syncthreads();
        float e = __expf(o6 - mx);
        red[j] = e; __syncthreads();
        for (int st = 128; st > 0; st >>= 1) {
            if (j < st) red[j] += red[j+st];
            __syncthreads();
        }
        float ga = e / red[0];
        int idx = s*NH + j;
        par[0*65536 + idx] = sigmoidf_(o0);
        par[1*65536 + idx] = sigmoidf_(o1);
        par[2*65536 + idx] = 0.1f * sigmoidf_(o2);
        par[3*65536 + idx] = sigmoidf_(o3);
        par[4*65536 + idx] = __expf(2.f * o4);
        par[5*65536 + idx] = fmaxf(o5, 0.f);
        par[6*65536 + idx] = ga;
        return;
    }

    // ---- gemm2 body: barrier-free register GEMM on fragment-tile layout ----
    int i_ = blockIdx.x - 256;         // 0..4415; 256 = 0 mod 8 keeps XCD swizzle
    int chunk = i_ / 48, rem = i_ % 48;
    int pair = chunk*8 + (rem & 7);
    int nt = rem >> 3;                 // 0..5
    int tg = pair >> 4, sg = pair & 15;
    int wave = tid >> 6, lane = tid & 63;
    int lr = lane & 15, lq = lane >> 4;
    int wn = (wave & 1)*64;
    int tj0 = (wave >> 1)*4;

    floatx4 acc[4][4];
#pragma unroll
    for (int i = 0; i < 4; ++i)
#pragma unroll
        for (int jj = 0; jj < 4; ++jj) acc[i][jj] = (floatx4)(0.f);

    // A tile (i, kg): mt = (tg*8 + tj0 + i)*16 + sg; u16 offset ((mt*8+kg)<<9) + lane*8
    //   i-stride = 16 tiles * 8 kg * 512 = 65536 u16; kg-stride = 512 u16
    // B tile (jj, kg): ntile = nt*8 + (wn>>4) + jj; jj-stride = 8*512 = 4096 u16
    const u16* Af = h1b + (((size_t)(((tg*8 + tj0)*16 + sg)*8)) << 9>> 9)*512 + (lane << 3);
    const u16* Bf = w2t + ((size_t)((nt*8 + (wn >> 4))*8))*512 + (lane << 3);

    short8 afr[2][4], bfr[2][4];
#pragma unroll
    for (int i = 0; i < 4; ++i)
        afr[0][i] = *(const short8*)(Af + (size_t)i*65536);
#pragma unroll
    for (int jj = 0; jj < 4; ++jj)
        bfr[0][jj] = *(const short8*)(Bf + jj*4096);

#pragma unroll
    for (int k = 0; k < 8; ++k) {
        int cur = k & 1, nxt = cur ^ 1;
        if (k < 7) {
#pragma unroll
            for (int i = 0; i < 4; ++i)
                afr[nxt][i] = *(const short8*)(Af + (size_t)i*65536 + (k+1)*512);
#pragma unroll
            for (int jj = 0; jj < 4; ++jj)
                bfr[nxt][jj] = *(const short8*)(Bf + jj*4096 + (k+1)*512);
        }
#pragma unroll
        for (int i = 0; i < 4; ++i)
#pragma unroll
            for (int jj = 0; jj < 4; ++jj)
                acc[i][jj] = __builtin_amdgcn_mfma_f32_16x16x32_bf16(afr[cur][i], bfr[cur][jj], acc[i][jj], 0, 0, 0);
    }

    int seg = nt >> 1;
    int hb = (nt & 1)*128 + wn;
    u16* plane = Pc + (size_t)seg * PSEG;
#pragma unroll
    for (int jj = 0; jj < 4; ++jj) {
        int h = hb + jj*16 + lr;
        float bias = b2[seg*256 + h];
#pragma unroll
        for (int rr = 0; rr < 4; ++rr) {
            int s = sg*16 + lq*4 + rr;
            short4v o4;
#pragma unroll
            for (int i = 0; i < 4; ++i) {
                int m = (tg*8 + tj0 + i)*256 + s;
                float v = acc[i][jj][rr] + bias;
                float o;
                if (seg == 0)      o = plc[m] * fminf(fmaxf(v*(1.f/3.f) + 0.5f, 0.f), 1.f);
                else if (seg == 1) o = e2[m] * fmaxf(v, 0.f);
                else               o = __expf(v);
                o4[i] = (short)f2bf(o);
            }
            int idx = s*256 + h;
            *(short4v*)(plane + ((size_t)(idx >> 6)*TC + tg)*512 + (idx & 63)*8 + tj0) = o4;
        }
    }
}

// ---------------- k_scanconv: scan + 16-tap conv; depth-3 prefetch PINNED with
// sched_barrier(0); LDS transpose reduction (stride-65, conflict-free) ----------------
__global__ __launch_bounds__(64, 1) void k_scanconv(const u16* __restrict__ Pc,
                                                    const float* __restrict__ ps,
                                                    const float* __restrict__ par,
                                                    const float* __restrict__ r,
                                                    float* __restrict__ out) {
    int g = blockIdx.x;                // 1024 groups of 64 (s,h) pairs
    int lane = threadIdx.x;
    int idx = g*64 + lane;
    int s = idx >> 8;
    __shared__ float s_ps[NT];
    __shared__ float sred[16*65];      // [j][lane] stride 65: writes & reads conflict-free
    for (int t = lane; t < NT; t += 64) s_ps[t] = ps[t*NS + s];
    float kp = par[idx], ks_ = par[65536+idx], kg = par[2*65536+idx],
          gp = par[3*65536+idx], gL = par[4*65536+idx], qb = par[5*65536+idx],
          ga = par[6*65536+idx];
    float rt[NR];
#pragma unroll
    for (int k = 0; k < NR; ++k) rt[k] = r[(size_t)idx*NR + k] * ga;
    __syncthreads();

    const u16* b0 = Pc + 0*PSEG + (size_t)g*TC*512 + lane*8;
    const u16* b1 = Pc + 1*PSEG + (size_t)g*TC*512 + lane*8;
    const u16* b2p= Pc + 2*PSEG + (size_t)g*TC*512 + lane*8;

    union U8 { short8 v; u16 u[8]; };
    U8 c0[6], c1[6], c2[6], c3[6];
#pragma unroll
    for (int hc = 0; hc < 2; ++hc) {
        c0[0 + hc].v = *(const short8*)(b0 + hc*512);
        c0[2 + hc].v = *(const short8*)(b1 + hc*512);
        c0[4 + hc].v = *(const short8*)(b2p + hc*512);
        c1[0 + hc].v = *(const short8*)(b0 + (2 + hc)*512);
        c1[2 + hc].v = *(const short8*)(b1 + (2 + hc)*512);
        c1[4 + hc].v = *(const short8*)(b2p + (2 + hc)*512);
        c2[0 + hc].v = *(const short8*)(b0 + (4 + hc)*512);
        c2[2 + hc].v = *(const short8*)(b1 + (4 + hc)*512);
        c2[4 + hc].v = *(const short8*)(b2p + (4 + hc)*512);
    }
    float Sf = 0.f, Ss = 0.f, Sg = 0.f;
    float qwin[16];
#pragma unroll
    for (int k = 0; k < 16; ++k) qwin[k] = 0.f;

    for (int blk = 0; blk < 23; ++blk) {
        int tbase = blk * 16;
        if (blk < 20) {                // depth-3 prefetch: chunk blk+3
            size_t o = (size_t)(2*blk + 6)*512;
#pragma unroll
            for (int hc = 0; hc < 2; ++hc) {
                c3[0 + hc].v = *(const short8*)(b0 + o + hc*512);
                c3[2 + hc].v = *(const short8*)(b1 + o + hc*512);
                c3[4 + hc].v = *(const short8*)(b2p + o + hc*512);
            }
        }
        __builtin_amdgcn_sched_barrier(0);   // pin prefetch issue BEFORE compute
        float cv[16];
#pragma unroll
        for (int j = 0; j < 16; ++j) cv[j] = 0.f;
#pragma unroll
        for (int j = 0; j < 16; ++j) {
            int t = tbase + j;
            if (t < NT) {
                float pl = bf2f(c0[0 + (j>>3)].u[j&7]);
                float ev = bf2f(c0[2 + (j>>3)].u[j&7]);
                float fm = bf2f(c0[4 + (j>>3)].u[j&7]);
                float fs = s_ps[t];
                float qf = fminf(Sf + fs, fm);
                Sf = fmaxf(Sf + fs - fm, 0.f);
                float H = fmaxf(Ss + pl + qf - ev, 0.f);
                float qp = fmaxf(kp * (H - gL), 0.f);
                float qsa = ks_ * fminf(H, gL);
                Ss = H - qp - qsa;
                float qsg = qsa * gp;
                float qs = qsa - qsg;
                float qg = kg * (Sg + qsg) + qb;
                Sg = (1.f - kg) * (Sg + qsg) - qb;
                float q = qp + qs + qg;
                qwin[j] = q;                 // slot t & 15 == j
                if (t >= 15) {
                    float c = 0.f;
#pragma unroll
                    for (int k = 0; k < 16; ++k) c += rt[k] * qwin[(j + 1 + k) & 15];
                    cv[j] = c;               // ga folded into rt
                }
            }
        }
#pragma unroll
        for (int pq = 0; pq < 6; ++pq) { c0[pq] = c1[pq]; c1[pq] = c2[pq]; c2[pq] = c3[pq]; }

        // LDS transpose reduction: Y[j] = sum over 64 lanes of cv[j]
#pragma unroll
        for (int j = 0; j < 16; ++j) sred[j*65 + lane] = cv[j];
        __syncthreads();               // 1 wave: cheap (lgkmcnt drain + nop barrier)
        {
            int j2 = lane & 15, q2 = lane >> 4;
            float p = 0.f;
#pragma unroll
            for (int i = 0; i < 16; ++i) p += sred[j2*65 + q2*16 + i];
            p += __shfl_xor(p, 16, 64);
            p += __shfl_xor(p, 32, 64);
            int tout = tbase + j2 - 15;
            if (lane < 16 && tout >= 0 && tout < TOUT)
                atomicAdd(out + tout*NS + s, p);
        }
        __syncthreads();               // sred reusable next iter
    }
}

// ---------------- launch ----------------
extern "C" void kernel_launch(void* const* d_in, const int* in_sizes, int n_in,
                              void* d_out, int out_size, void* d_ws, size_t ws_size,
                              hipStream_t stream) {
    const float* x   = (const float*)d_in[0];
    const float* xc  = (const float*)d_in[1];
    const float* fw1 = (const float*)d_in[2];
    const float* fb1 = (const float*)d_in[3];
    const float* fw2 = (const float*)d_in[4];
    const float* fb2 = (const float*)d_in[5];
    const float* tw1 = (const float*)d_in[6];
    const float* tb1 = (const float*)d_in[7];
    const float* tw2 = (const float*)d_in[8];
    const float* tb2 = (const float*)d_in[9];
    const float* rw1 = (const float*)d_in[10];
    const float* rb1 = (const float*)d_in[11];
    const float* rw2 = (const float*)d_in[12];
    const float* rb2 = (const float*)d_in[13];
    float* out = (float*)d_out;
    char* ws = (char*)d_ws;

    // workspace layout (bytes); peak = 202,326,016 (wlog in own region)
    constexpr size_t OFF_PS    = 0;              //   376,832 (padded to MPAD)
    constexpr size_t OFF_PLC   = 376832;         //   376,832
    constexpr size_t OFF_E2    = 753664;         //   376,832
    constexpr size_t OFF_PAR   = 1130496;        // 1,835,008
    constexpr size_t OFF_R     = 2965504;        // 4,194,304
    constexpr size_t OFF_W2TT  = 7159808;        //   393,216
    constexpr size_t OFF_H1B   = 7553024;        // 48,234,496 (MPAD rows)
    constexpr size_t OFF_PC    = 55787520;       // 144,703,488 -> 200,491,008
    constexpr size_t OFF_WLOG  = 200491008;      // 1,835,008 -> 202,326,016 (own region)
    // overlays inside Pc region (dead before k_g2p writes Pc):
    constexpr size_t OFF_W2TW  = OFF_PC + 0;           //   917,504
    constexpr size_t OFF_W2TR  = OFF_PC + 917504;      // 2,097,152
    constexpr size_t OFF_H1W   = OFF_PC + 3014656;     //   131,072
    constexpr size_t OFF_H1R   = OFF_PC + 3145728;     //   131,072

    float* ps    = (float*)(ws + OFF_PS);
    float* plc   = (float*)(ws + OFF_PLC);
    float* e2    = (float*)(ws + OFF_E2);
    float* par   = (float*)(ws + OFF_PAR);
    float* rbuf  = (float*)(ws + OFF_R);
    u16*   w2tT  = (u16*)(ws + OFF_W2TT);
    u16*   h1b   = (u16*)(ws + OFF_H1B);
    u16*   Pc    = (u16*)(ws + OFF_PC);
    float* wlog  = (float*)(ws + OFF_WLOG);
    u16*   w2tW  = (u16*)(ws + OFF_W2TW);
    u16*   w2tR  = (u16*)(ws + OFF_W2TR);
    u16*   h1W   = (u16*)(ws + OFF_H1W);
    u16*   h1R   = (u16*)(ws + OFF_H1R);

    k_prep     <<<813, 256, 0, stream>>>(x, ps, plc, e2, out,
                                         tw2, w2tT, fw2, w2tW, rw2, w2tR,
                                         xc, fw1, fb1, rw1, rb1, h1W, h1R);
    k_mid      <<<3036, 256, 0, stream>>>(h1W, w2tW, fb2, wlog,
                                          h1R, w2tR, rb2, rbuf,
                                          x, xc, tw1, tb1, h1b);
    k_g2p      <<<256 + TC*16*6, 256, 0, stream>>>(h1b, w2tT, tb2, plc, e2, Pc, wlog, par);
    k_scanconv <<<1024, 64, 0, stream>>>(Pc, ps, par, rbuf, out);
}

// Round 4
// 288.089 us; speedup vs baseline: 1.2794x; 1.2794x over previous
//
#include <hip/hip_runtime.h>

// Problem constants
#define NT   365
#define NS   256
#define NH   256
#define NG   32
#define NR   16
#define HID  256
#define NX   38           // 6 + NG
#define M_   (NT*NS)      // 93440
#define TOUT (NT-NR+1)    // 350

typedef __attribute__((ext_vector_type(8))) short short8;
typedef __attribute__((ext_vector_type(4))) float floatx4;
typedef unsigned short u16;

__device__ __forceinline__ u16 f2bf(float f) {
    unsigned u = __float_as_uint(f);
    u = (u + 0x7FFFu + ((u >> 16) & 1u)) >> 16;   // RNE
    return (u16)u;
}
__device__ __forceinline__ float sigmoidf_(float x) { return 1.f / (1.f + __expf(-x)); }

// Fragment-tile layout (R17-proven): a 16x32 bf16 MFMA tile is stored as
// 64 lanes x 8 u16 contiguous (1 KB). Element (r, c) lives at
// lane = (r&15) | (((c&31)>>3)<<4), pos = c&7.
// R18: h1b tiles are (s, t-tile): row = t&15, tile idx = (s*23 + tt)*8 + kg
//      (s-stride = 23*8*512 = 94208 u16).
//      w2tT tiles unchanged: tile idx = ntile*8 + kg, ntile = n>>4.

// ---------------- k_prep: pre(365) + cvtT3(416) + mlp1(32) = 813 blocks ----------------
__global__ __launch_bounds__(256) void k_prep(const float* __restrict__ x,
                                              float* __restrict__ psT, float* __restrict__ plcT,
                                              float* __restrict__ e2T, float* __restrict__ out,
                                              const float* __restrict__ tw2, u16* __restrict__ w2tT,
                                              const float* __restrict__ fw2, u16* __restrict__ w2tW,
                                              const float* __restrict__ rw2, u16* __restrict__ w2tR,
                                              const float* __restrict__ xc,
                                              const float* __restrict__ wW, const float* __restrict__ bW,
                                              const float* __restrict__ wR, const float* __restrict__ bR,
                                              u16* __restrict__ h1W, u16* __restrict__ h1R) {
    int bx = blockIdx.x, tid = threadIdx.x;
    if (bx < 365) {
        // ---- pre body (+ zero out); outputs transposed [s][368] for fused scan ----
        int m = bx * 256 + tid;          // t = bx, s = tid
        if (m < TOUT*NS) out[m] = 0.f;
        float P  = x[m*6+0], E = x[m*6+1], T1 = x[m*6+2], T2 = x[m*6+3];
        float vf;
        if (T2 <= 0.f)      vf = 1.f;
        else if (T1 >= 0.f) vf = 0.f;
        else {
            float ratio = (T1 + T2) / (T2 - T1);
            ratio = fminf(fmaxf(ratio, -1.f), 1.f);
            vf = acosf(ratio) * (1.f / 3.1415f);
        }
        psT[tid*368 + bx]  = P * vf;
        plcT[tid*368 + bx] = P * (1.f - vf);
        e2T[tid*368 + bx]  = 2.f * E;
    } else if (bx < 781) {
        // ---- cvtT3 body ----
        __shared__ u16 tile[64][65];
        int i2 = bx - 365;
        int bn_ = i2 % 104, bk = i2 / 104;
        const float* w; u16* wt; int N, bn; bool frag;
        if (bn_ < 12)      { w = tw2; wt = w2tT; N = 768;  bn = bn_;      frag = true;  }
        else if (bn_ < 40) { w = fw2; wt = w2tW; N = 1792; bn = bn_ - 12; frag = false; }
        else               { w = rw2; wt = w2tR; N = 4096; bn = bn_ - 40; frag = false; }
        for (int i = tid; i < 64*64; i += 256) {
            int kk = i >> 6, nn = i & 63;
            tile[nn][kk] = f2bf(w[(size_t)(bk*64 + kk)*N + bn*64 + nn]);
        }
        __syncthreads();
        for (int i = tid; i < 64*64; i += 256) {
            int nn = i >> 6, kk = i & 63;
            int n = bn*64 + nn, k = bk*64 + kk;
            if (frag) {
                int ntile = n >> 4, kg = k >> 5;
                int lane2 = (n & 15) | (((k & 31) >> 3) << 4);
                wt[(((size_t)(ntile*8 + kg)) << 9) + (lane2 << 3) + (k & 7)] = tile[nn][kk];
            } else {
                wt[(size_t)n*256 + k] = tile[nn][kk];
            }
        }
    } else {
        // ---- mlp1 body ----
        int b = bx - 781;                       // 0..31: net*16 + grp
        int net = b >> 4, grp = b & 15;
        const float* w1 = net ? wR : wW;
        const float* b1 = net ? bR : bW;
        u16* o = net ? h1R : h1W;
        int s0 = grp * 16, j = tid;
        __shared__ float xs1[16][NG];
        for (int i = j; i < 16*NG; i += 256) xs1[i >> 5][i & 31] = xc[s0*NG + i];
        __syncthreads();
        float acc[16];
        float bb = b1[j];
#pragma unroll
        for (int si = 0; si < 16; ++si) acc[si] = bb;
        for (int g = 0; g < NG; ++g) {
            float w = w1[g*HID + j];
#pragma unroll
            for (int si = 0; si < 16; ++si) acc[si] += xs1[si][g] * w;
        }
#pragma unroll
        for (int si = 0; si < 16; ++si) o[(s0 + si)*256 + j] = f2bf(tanhf(acc[si]));
    }
}

// ---------------- k_mid: gemmS<0>(28) + gemmS<1>(64) + fcT1(2944) = 3036 blocks ----------------
__global__ __launch_bounds__(256) void k_mid(const u16* __restrict__ h1W, const u16* __restrict__ w2tW,
                                             const float* __restrict__ fb2, float* __restrict__ wlog,
                                             const u16* __restrict__ h1R, const u16* __restrict__ w2tR,
                                             const float* __restrict__ rb2, float* __restrict__ rbuf,
                                             const float* __restrict__ x, const float* __restrict__ xc,
                                             const float* __restrict__ tw1, const float* __restrict__ tb1,
                                             u16* __restrict__ h1b) {
    int bx = blockIdx.x, tid = threadIdx.x;
    if (bx < 92) {
        // ---- gemmS body (mode 0: bx<28, mode 1: else) ----
        int mode, bm, bn, Nn;
        const u16 *A, *B; const float* bias; float* outp;
        if (bx < 28) { mode = 0; bm = bx % 2;        bn = bx / 2;        Nn = 1792; A = h1W; B = w2tW; bias = fb2; outp = wlog; }
        else         { mode = 1; bm = (bx - 28) % 2; bn = (bx - 28) / 2; Nn = 4096; A = h1R; B = w2tR; bias = rb2; outp = rbuf; }
        int wave = tid >> 6, lane = tid & 63;
        __shared__ __align__(16) u16 As[128*32];
        __shared__ __align__(16) u16 Bs[128*32];
        floatx4 acc[4][4];
#pragma unroll
        for (int i = 0; i < 4; ++i)
#pragma unroll
            for (int jj = 0; jj < 4; ++jj) acc[i][jj] = (floatx4)(0.f);
        int m0 = bm*128, n0 = bn*128;
        int rA = tid >> 2, cA = (tid & 3) * 8;
        int wm = (wave >> 1)*64, wn = (wave & 1)*64, lr = lane & 15, lq = lane >> 4;
        for (int k0 = 0; k0 < 256; k0 += 32) {
            short8 a0  = *(const short8*)(A + (m0 + rA     )*256 + k0 + cA);
            short8 a1  = *(const short8*)(A + (m0 + rA + 64)*256 + k0 + cA);
            short8 bv0 = *(const short8*)(B + (n0 + rA     )*256 + k0 + cA);
            short8 bv1 = *(const short8*)(B + (n0 + rA + 64)*256 + k0 + cA);
            __syncthreads();
            *(short8*)(As + rA*32 + cA)        = a0;
            *(short8*)(As + (rA + 64)*32 + cA) = a1;
            *(short8*)(Bs + rA*32 + cA)        = bv0;
            *(short8*)(Bs + (rA + 64)*32 + cA) = bv1;
            __syncthreads();
            short8 af[4], bf[4];
#pragma unroll
            for (int i = 0; i < 4; ++i)
                af[i] = *(const short8*)(As + (wm + i*16 + lr)*32 + lq*8);
#pragma unroll
            for (int jj = 0; jj < 4; ++jj)
                bf[jj] = *(const short8*)(Bs + (wn + jj*16 + lr)*32 + lq*8);
#pragma unroll
            for (int i = 0; i < 4; ++i)
#pragma unroll
                for (int jj = 0; jj < 4; ++jj)
                    acc[i][jj] = __builtin_amdgcn_mfma_f32_16x16x32_bf16(af[i], bf[jj], acc[i][jj], 0, 0, 0);
        }
#pragma unroll
        for (int jj = 0; jj < 4; ++jj) {
            int n_glob = n0 + wn + jj*16 + lr;
            float bv = bias[n_glob];
            int hg = (n0 + wn + jj*16) >> 4;
#pragma unroll
            for (int i = 0; i < 4; ++i) {
#pragma unroll
                for (int rr = 0; rr < 4; ++rr) {
                    int m = m0 + wm + i*16 + lq*4 + rr;
                    float v = acc[i][jj][rr] + bv;
                    if (mode == 0) {
                        outp[(size_t)m*Nn + n_glob] = v;
                    } else {
                        v = fmaxf(v, 0.f);
                        float mx = v;
#pragma unroll
                        for (int d = 1; d < 16; d <<= 1) mx = fmaxf(mx, __shfl_xor(mx, d, 64));
                        float e = __expf(v - mx);
                        float sm = e;
#pragma unroll
                        for (int d = 1; d < 16; d <<= 1) sm += __shfl_xor(sm, d, 64);
                        outp[(size_t)m*4096 + hg*16 + lr] = e / sm;
                    }
                }
            }
        }
    } else {
        // ---- fcT1 body: writes h1b in (s, t-tile) fragment layout ----
        int m0 = (bx - 92) * 32;           // 32 consecutive m = fixed t, 32 consecutive s
        int j = tid;
        __shared__ float xs[32][NX + 2];
        for (int idx = j; idx < 32*NX; idx += 256) {
            int rr = idx / NX, c = idx % NX;
            int m = m0 + rr;
            int mc = m < M_ ? m : M_ - 1;
            int s = mc & (NS - 1);
            xs[rr][c] = (c < 6) ? x[mc*6 + c] : xc[s*NG + (c - 6)];
        }
        __syncthreads();
        float acc[32];
        float b = tb1[j];
#pragma unroll
        for (int rr = 0; rr < 32; ++rr) acc[rr] = b;
        for (int g = 0; g < NX; ++g) {
            float w = tw1[g*HID + j];
#pragma unroll
            for (int rr = 0; rr < 32; ++rr) acc[rr] += xs[rr][g] * w;
        }
        int t_  = m0 >> 8;                 // constant within block (m0%256 <= 224)
        int tt_ = t_ >> 4, tr_ = t_ & 15;
        int s0_ = m0 & 255;
        int kg_ = j >> 5;
        int lane2 = tr_ | (((j & 31) >> 3) << 4);
        int pos = j & 7;
        size_t base = ((((size_t)tt_)*8 + kg_) << 9) + (lane2 << 3) + pos;
#pragma unroll
        for (int rr = 0; rr < 32; ++rr) {
            int s_ = s0_ + rr;
            h1b[(size_t)s_*94208 + base] = f2bf(tanhf(acc[rr]));
        }
    }
}

// ---------------- k_post: fcw_post standalone (256 blocks) ----------------
__global__ __launch_bounds__(256) void k_post(const float* __restrict__ wlog,
                                              float* __restrict__ par) {
    __shared__ float red[256];
    int s = blockIdx.x, j = threadIdx.x;
    const float* L = wlog + (size_t)s*1792;
    float o0 = L[j], o1 = L[256+j], o2 = L[512+j], o3 = L[768+j],
          o4 = L[1024+j], o5 = L[1280+j], o6 = L[1536+j];
    red[j] = o6; __syncthreads();
    for (int st = 128; st > 0; st >>= 1) {
        if (j < st) red[j] = fmaxf(red[j], red[j+st]);
        __syncthreads();
    }
    float mx = red[0]; __syncthreads();
    float e = __expf(o6 - mx);
    red[j] = e; __syncthreads();
    for (int st = 128; st > 0; st >>= 1) {
        if (j < st) red[j] += red[j+st];
        __syncthreads();
    }
    float ga = e / red[0];
    int idx = s*NH + j;
    par[0*65536 + idx] = sigmoidf_(o0);
    par[1*65536 + idx] = sigmoidf_(o1);
    par[2*65536 + idx] = 0.1f * sigmoidf_(o2);
    par[3*65536 + idx] = sigmoidf_(o3);
    par[4*65536 + idx] = __expf(2.f * o4);
    par[5*65536 + idx] = fmaxf(o5, 0.f);
    par[6*65536 + idx] = ga;
}

// ---------------- k_scanfuse: in-register GEMM (B resident) + scan + conv ----------------
// 1024 blocks x 64 threads (1 wave); block = (4 s, 16 h); Pc eliminated.
__global__ __launch_bounds__(64, 1) void k_scanfuse(const u16* __restrict__ h1b,
                                                    const u16* __restrict__ w2t,
                                                    const float* __restrict__ b2,
                                                    const float* __restrict__ psT,
                                                    const float* __restrict__ plcT,
                                                    const float* __restrict__ e2T,
                                                    const float* __restrict__ par,
                                                    const float* __restrict__ r,
                                                    float* __restrict__ out) {
    int bx = blockIdx.x;
    int sgrp = bx >> 4, hb = bx & 15;
    int lane = threadIdx.x;
    int h_idx = lane & 15, s_idx = lane >> 4;    // MFMA D: col=lane&15 (h), row=s_idx*4+reg (t)
    int s_g = sgrp*4 + s_idx, h_g = hb*16 + h_idx;
    int pidx = s_g*NH + h_g;

    __shared__ float s_ps[4][368];
    __shared__ float s_plc[4][368];
    __shared__ float s_e2[4][368];
    __shared__ float xbuf[4*872];   // base(si,seg)=si*872+seg*288, row stride 18

#pragma unroll
    for (int si = 0; si < 4; ++si) {
        int sg = sgrp*4 + si;
        for (int t = lane; t < 368; t += 64) {
            bool v = (t < NT);
            s_ps[si][t]  = v ? psT[sg*368 + t]  : 0.f;
            s_plc[si][t] = v ? plcT[sg*368 + t] : 0.f;
            s_e2[si][t]  = v ? e2T[sg*368 + t]  : 0.f;
        }
    }

    float kp = par[pidx], ks_ = par[65536+pidx], kg = par[2*65536+pidx],
          gp = par[3*65536+pidx], gL = par[4*65536+pidx], qb = par[5*65536+pidx],
          ga = par[6*65536+pidx];
    float rt[NR];
#pragma unroll
    for (int k = 0; k < NR; ++k) rt[k] = r[(size_t)pidx*NR + k] * ga;
    float bias0 = b2[0*256 + h_g], bias1 = b2[1*256 + h_g], bias2 = b2[2*256 + h_g];

    short8 Bv[3][8];
#pragma unroll
    for (int sg2 = 0; sg2 < 3; ++sg2)
#pragma unroll
        for (int kgi = 0; kgi < 8; ++kgi)
            Bv[sg2][kgi] = *(const short8*)(w2t + (((size_t)((sg2*16 + hb)*8 + kgi)) << 9) + (lane << 3));

    const u16* Ab = h1b + (size_t)(sgrp*4)*94208 + (lane << 3);
    short8 Av[4][8];
#pragma unroll
    for (int si = 0; si < 4; ++si)
#pragma unroll
        for (int kgi = 0; kgi < 8; ++kgi)
            Av[si][kgi] = *(const short8*)(Ab + (size_t)si*94208 + kgi*512);

    __syncthreads();

    float Sf = 0.f, Ss = 0.f, Sg = 0.f;
    float qwin[16];
#pragma unroll
    for (int k = 0; k < 16; ++k) qwin[k] = 0.f;
    float* sredp = xbuf;

    for (int blk = 0; blk < 23; ++blk) {
        int tbase = blk * 16;
        floatx4 acc[4][3];
#pragma unroll
        for (int si = 0; si < 4; ++si)
#pragma unroll
            for (int sg2 = 0; sg2 < 3; ++sg2) acc[si][sg2] = (floatx4)(0.f);
#pragma unroll
        for (int kgi = 0; kgi < 8; ++kgi)
#pragma unroll
            for (int si = 0; si < 4; ++si)
#pragma unroll
                for (int sg2 = 0; sg2 < 3; ++sg2)
                    acc[si][sg2] = __builtin_amdgcn_mfma_f32_16x16x32_bf16(Av[si][kgi], Bv[sg2][kgi], acc[si][sg2], 0, 0, 0);
        if (blk < 22) {
            const u16* An = Ab + (size_t)(blk+1)*4096;
#pragma unroll
            for (int si = 0; si < 4; ++si)
#pragma unroll
                for (int kgi = 0; kgi < 8; ++kgi)
                    Av[si][kgi] = *(const short8*)(An + (size_t)si*94208 + kgi*512);
        }
        __builtin_amdgcn_sched_barrier(0);
#pragma unroll
        for (int si = 0; si < 4; ++si) {
#pragma unroll
            for (int rr = 0; rr < 4; ++rr) {
                int trow = s_idx*4 + rr;
                int t = tbase + trow;
                float v0 = acc[si][0][rr] + bias0;
                float v1 = acc[si][1][rr] + bias1;
                float v2 = acc[si][2][rr] + bias2;
                float pl = s_plc[si][t] * fminf(fmaxf(v0*(1.f/3.f) + 0.5f, 0.f), 1.f);
                float ev = s_e2[si][t] * fmaxf(v1, 0.f);
                float fm = __expf(v2);
                xbuf[si*872 + 0*288 + trow*18 + h_idx] = pl;
                xbuf[si*872 + 1*288 + trow*18 + h_idx] = ev;
                xbuf[si*872 + 2*288 + trow*18 + h_idx] = fm;
            }
        }
        __syncthreads();
        float cv[16];
#pragma unroll
        for (int j = 0; j < 16; ++j) cv[j] = 0.f;
#pragma unroll
        for (int j = 0; j < 16; ++j) {
            int t = tbase + j;
            if (t < NT) {
                float pl = xbuf[s_idx*872 + 0*288 + j*18 + h_idx];
                float ev = xbuf[s_idx*872 + 1*288 + j*18 + h_idx];
                float fm = xbuf[s_idx*872 + 2*288 + j*18 + h_idx];
                float fs = s_ps[s_idx][t];
                float qf = fminf(Sf + fs, fm);
                Sf = fmaxf(Sf + fs - fm, 0.f);
                float H = fmaxf(Ss + pl + qf - ev, 0.f);
                float qp = fmaxf(kp * (H - gL), 0.f);
                float qsa = ks_ * fminf(H, gL);
                Ss = H - qp - qsa;
                float qsg = qsa * gp;
                float qs = qsa - qsg;
                float qg = kg * (Sg + qsg) + qb;
                Sg = (1.f - kg) * (Sg + qsg) - qb;
                float q = qp + qs + qg;
                qwin[j] = q;
                if (t >= 15) {
                    float c = 0.f;
#pragma unroll
                    for (int k = 0; k < 16; ++k) c += rt[k] * qwin[(j + 1 + k) & 15];
                    cv[j] = c;
                }
            }
        }
        __syncthreads();
#pragma unroll
        for (int j = 0; j < 16; ++j) sredp[j*65 + lane] = cv[j];
        __syncthreads();
        {
            int j2 = lane & 15, q2 = lane >> 4;
            float p = 0.f;
#pragma unroll
            for (int i = 0; i < 16; ++i) p += sredp[j2*65 + q2*16 + i];
            int tout = tbase + j2 - 15;
            if (tout >= 0 && tout < TOUT)
                atomicAdd(out + tout*NS + sgrp*4 + q2, p);
        }
        __syncthreads();
    }
}

// ---------------- launch ----------------
extern "C" void kernel_launch(void* const* d_in, const int* in_sizes, int n_in,
                              void* d_out, int out_size, void* d_ws, size_t ws_size,
                              hipStream_t stream) {
    const float* x   = (const float*)d_in[0];
    const float* xc  = (const float*)d_in[1];
    const float* fw1 = (const float*)d_in[2];
    const float* fb1 = (const float*)d_in[3];
    const float* fw2 = (const float*)d_in[4];
    const float* fb2 = (const float*)d_in[5];
    const float* tw1 = (const float*)d_in[6];
    const float* tb1 = (const float*)d_in[7];
    const float* tw2 = (const float*)d_in[8];
    const float* tb2 = (const float*)d_in[9];
    const float* rw1 = (const float*)d_in[10];
    const float* rb1 = (const float*)d_in[11];
    const float* rw2 = (const float*)d_in[12];
    const float* rb2 = (const float*)d_in[13];
    float* out = (float*)d_out;
    char* ws = (char*)d_ws;

    constexpr size_t OFF_PS    = 0;              //   376,832  [s][368] f32
    constexpr size_t OFF_PLC   = 376832;
    constexpr size_t OFF_E2    = 753664;
    constexpr size_t OFF_PAR   = 1130496;        // 1,835,008
    constexpr size_t OFF_R     = 2965504;        // 4,194,304
    constexpr size_t OFF_W2TT  = 7159808;        //   393,216
    constexpr size_t OFF_H1B   = 7553024;        // 48,234,496 (s-major frag tiles)
    constexpr size_t OFF_PC    = 55787520;       // overlays only now
    constexpr size_t OFF_WLOG  = 200491008;      // 1,835,008
    constexpr size_t OFF_W2TW  = OFF_PC + 0;
    constexpr size_t OFF_W2TR  = OFF_PC + 917504;
    constexpr size_t OFF_H1W   = OFF_PC + 3014656;
    constexpr size_t OFF_H1R   = OFF_PC + 3145728;

    float* psT   = (float*)(ws + OFF_PS);
    float* plcT  = (float*)(ws + OFF_PLC);
    float* e2T   = (float*)(ws + OFF_E2);
    float* par   = (float*)(ws + OFF_PAR);
    float* rbuf  = (float*)(ws + OFF_R);
    u16*   w2tT  = (u16*)(ws + OFF_W2TT);
    u16*   h1b   = (u16*)(ws + OFF_H1B);
    float* wlog  = (float*)(ws + OFF_WLOG);
    u16*   w2tW  = (u16*)(ws + OFF_W2TW);
    u16*   w2tR  = (u16*)(ws + OFF_W2TR);
    u16*   h1W   = (u16*)(ws + OFF_H1W);
    u16*   h1R   = (u16*)(ws + OFF_H1R);

    k_prep     <<<813, 256, 0, stream>>>(x, psT, plcT, e2T, out,
                                         tw2, w2tT, fw2, w2tW, rw2, w2tR,
                                         xc, fw1, fb1, rw1, rb1, h1W, h1R);
    k_mid      <<<3036, 256, 0, stream>>>(h1W, w2tW, fb2, wlog,
                                          h1R, w2tR, rb2, rbuf,
                                          x, xc, tw1, tb1, h1b);
    k_post     <<<256, 256, 0, stream>>>(wlog, par);
    k_scanfuse <<<1024, 64, 0, stream>>>(h1b, w2tT, tb2, psT, plcT, e2T, par, rbuf, out);
}